// Round 1
// baseline (2196.446 us; speedup 1.0000x reference)
//
#include <hip/hip_runtime.h>
#include <cstdint>
#include <cstddef>

// ---------------------------------------------------------------------------
// BatchTreeEncoder: A=4, D=7, B=64, E=128, H=128, 3H=384, N_NODES=5461
// Levels d=6..0; level d has n=4^d nodes at row offset (4^d-1)/3 in tokens.
//   d==6: h0 = 0  (=> gh = b_hh, skip gh GEMM)
//   d<6 : child-attention over the 4 children produces h0, then GRU.
// Output: running elementwise max over levels of hn.max(axis=0) -> (64,128).
// ---------------------------------------------------------------------------

// workspace layout (bytes)
#define WS_ACC_OFF  0u                          // 8192 * 4  (encoded-max acc)
#define WS_SWT_OFF  32768u                      // 128*128*4 (sent_w transposed)
#define WS_HA_OFF   98304u                      // 4096*64*128*4 = 128 MB
#define WS_HB_OFF   (98304u + 134217728u)       // 1024*64*128*4 = 32 MB
#define WS_H0_OFF   (WS_HB_OFF + 33554432u)     // 32 MB
// total ~201.4 MB

__device__ __forceinline__ float sigm(float x)  { return 1.0f / (1.0f + __expf(-x)); }
__device__ __forceinline__ float tanhf_(float x){ return 1.0f - 2.0f / (1.0f + __expf(2.0f * x)); }

// monotone encode: preserves float order under unsigned compare; 0 < enc(any finite)
__device__ __forceinline__ unsigned fenc(float f) {
  unsigned u = __float_as_uint(f);
  return (u & 0x80000000u) ? ~u : (u | 0x80000000u);
}
__device__ __forceinline__ float fdec(unsigned e) {
  unsigned u = (e & 0x80000000u) ? (e & 0x7fffffffu) : ~e;
  return __uint_as_float(u);
}

__global__ __launch_bounds__(256) void init_acc(unsigned* __restrict__ acc) {
  acc[blockIdx.x * 256 + threadIdx.x] = 0u;
}

__global__ __launch_bounds__(256) void decode_out(const unsigned* __restrict__ acc,
                                                  float* __restrict__ out) {
  int i = blockIdx.x * 256 + threadIdx.x;
  out[i] = fdec(acc[i]);
}

// swT[k][h] = sent_w[h][k]  (so attention reads contiguous rows with scalar loads)
__global__ __launch_bounds__(256) void prep_swt(const float* __restrict__ sw,
                                                float* __restrict__ swT) {
  int i = blockIdx.x * 256 + threadIdx.x;   // 16384
  int k = i >> 7, h = i & 127;
  swT[i] = sw[h * 128 + k];
}

// ---------------------------------------------------------------------------
// GRU kernel: one workgroup per (node, j-slice). 256 threads = 4 waves.
// lane = b (batch), wave wq owns output channels j = wq + 4*i.
// Weight rows are wave-uniform => scalar (s_load_dwordx4) streaming.
// x and h0 staged in LDS, 32 KB each, chunk-rotated to balance banks.
// ---------------------------------------------------------------------------
template <bool HAS_H>
__global__ __launch_bounds__(256) void gru_kernel(
    const int*   __restrict__ tok,    // n*64 (already offset to level)
    const float* __restrict__ emb,    // V x 128
    const float* __restrict__ w_ih,   // 384 x 128
    const float* __restrict__ w_hh,   // 384 x 128
    const float* __restrict__ b_ih,   // 384
    const float* __restrict__ b_hh,   // 384
    const float* __restrict__ h0,     // n*64*128 or null
    float*       __restrict__ hout)   // n*64*128
{
  __shared__ float xs[8192];
  __shared__ float hs[HAS_H ? 8192 : 4];

  const int node = blockIdx.x;
  const int t = threadIdx.x;

  // stage x (emb gather) and h0 into LDS, swizzled: row b, float4-chunk q at (q+b)&31
#pragma unroll
  for (int i = 0; i < 8; ++i) {
    int f = t + 256 * i;            // float4 id, 2048 total
    int b = f >> 5, q = f & 31;
    int tk = tok[node * 64 + b];
    *(float4*)(xs + (b << 7) + (((q + b) & 31) << 2)) =
        *(const float4*)(emb + (size_t)tk * 128 + (q << 2));
    if constexpr (HAS_H) {
      *(float4*)(hs + (b << 7) + (((q + b) & 31) << 2)) =
          *(const float4*)(h0 + (size_t)node * 8192 + (f << 2));
    }
  }
  __syncthreads();

  const int b = t & 63;
  const int wq = __builtin_amdgcn_readfirstlane(t >> 6);   // wave id -> uniform
  float* outp = hout + (size_t)node * 8192 + b * 128;

  const int jper = 32 / gridDim.y;          // j-split for small levels
  const int ibase = blockIdx.y * jper;

  for (int i = ibase; i < ibase + jper; ++i) {
    const int j = wq + 4 * i;               // uniform within wave
    float gr = b_ih[j], gz = b_ih[j + 128], gn = b_ih[j + 256];
    float hr = b_hh[j], hz = b_hh[j + 128], hn = b_hh[j + 256];
    const float* wr = w_ih + (size_t)j * 128;
    const float* wz = wr + 16384;
    const float* wn = wr + 32768;
    const float* vr = w_hh + (size_t)j * 128;
    const float* vz = vr + 16384;
    const float* vn = vr + 32768;

#pragma unroll 4
    for (int q = 0; q < 32; ++q) {
      float4 xv = *(const float4*)(xs + (b << 7) + (((q + b) & 31) << 2));
      float4 w0 = *(const float4*)(wr + (q << 2));
      float4 w1 = *(const float4*)(wz + (q << 2));
      float4 w2 = *(const float4*)(wn + (q << 2));
      gr += xv.x * w0.x + xv.y * w0.y + xv.z * w0.z + xv.w * w0.w;
      gz += xv.x * w1.x + xv.y * w1.y + xv.z * w1.z + xv.w * w1.w;
      gn += xv.x * w2.x + xv.y * w2.y + xv.z * w2.z + xv.w * w2.w;
      if constexpr (HAS_H) {
        float4 hv = *(const float4*)(hs + (b << 7) + (((q + b) & 31) << 2));
        float4 v0 = *(const float4*)(vr + (q << 2));
        float4 v1 = *(const float4*)(vz + (q << 2));
        float4 v2 = *(const float4*)(vn + (q << 2));
        hr += hv.x * v0.x + hv.y * v0.y + hv.z * v0.z + hv.w * v0.w;
        hz += hv.x * v1.x + hv.y * v1.y + hv.z * v1.z + hv.w * v1.w;
        hn += hv.x * v2.x + hv.y * v2.y + hv.z * v2.z + hv.w * v2.w;
      }
    }
    float r  = sigm(gr + hr);
    float z  = sigm(gz + hz);
    float nv = tanhf_(gn + r * hn);
    float hprev = 0.0f;
    if constexpr (HAS_H) {
      // h0[b][j], j = 4*i + wq -> chunk i, sub-offset wq
      hprev = hs[(b << 7) + (((i + b) & 31) << 2) + wq];
    }
    outp[j] = (1.0f - z) * nv + z * hprev;
  }
}

// ---------------------------------------------------------------------------
// Attention: one workgroup per parent node. Loop a=0..3: stage child slab
// (64x128, 32 KB) in LDS, 4 waves split the k-range, lane = b.
// s[a][b] = tanh( sum_k tanh(ch_row . swT[k] + sb[k]) * ctx[k] )
// then softmax over a and h0 = sum_a alpha_a * ch_a (children re-read from L2).
// ---------------------------------------------------------------------------
__global__ __launch_bounds__(256) void attn_kernel(
    const float* __restrict__ child,  // (4n)*64*128
    const float* __restrict__ swT,    // 128x128, k-major
    const float* __restrict__ sb,     // 128
    const float* __restrict__ ctx,    // 128
    float*       __restrict__ h0)     // n*64*128
{
  __shared__ float chs[8192];
  __shared__ float part[256];
  __shared__ float svals[256];

  const int node = blockIdx.x;
  const int t = threadIdx.x;
  const int w = __builtin_amdgcn_readfirstlane(t >> 6);
  const int lane = t & 63;

  for (int a = 0; a < 4; ++a) {
    const float* src = child + ((size_t)(node * 4 + a)) * 8192;
    __syncthreads();  // protect chs from previous iteration's readers
#pragma unroll
    for (int i = 0; i < 8; ++i) {
      int f = t + 256 * i;
      int b = f >> 5, q = f & 31;
      *(float4*)(chs + (b << 7) + (((q + b) & 31) << 2)) = *(const float4*)(src + (f << 2));
    }
    __syncthreads();

    float accs = 0.0f;
    for (int kk = 0; kk < 32; kk += 4) {
      const int k = (w << 5) + kk;          // uniform within wave
      float u0 = sb[k], u1 = sb[k + 1], u2 = sb[k + 2], u3 = sb[k + 3];
      const float* r0 = swT + ((size_t)k << 7);
      const float* r1 = r0 + 128;
      const float* r2 = r0 + 256;
      const float* r3 = r0 + 384;
#pragma unroll 4
      for (int q = 0; q < 32; ++q) {
        float4 cv = *(const float4*)(chs + (lane << 7) + (((q + lane) & 31) << 2));
        float4 a0 = *(const float4*)(r0 + (q << 2));
        float4 a1 = *(const float4*)(r1 + (q << 2));
        float4 a2 = *(const float4*)(r2 + (q << 2));
        float4 a3 = *(const float4*)(r3 + (q << 2));
        u0 += cv.x * a0.x + cv.y * a0.y + cv.z * a0.z + cv.w * a0.w;
        u1 += cv.x * a1.x + cv.y * a1.y + cv.z * a1.z + cv.w * a1.w;
        u2 += cv.x * a2.x + cv.y * a2.y + cv.z * a2.z + cv.w * a2.w;
        u3 += cv.x * a3.x + cv.y * a3.y + cv.z * a3.z + cv.w * a3.w;
      }
      accs += tanhf_(u0) * ctx[k] + tanhf_(u1) * ctx[k + 1] +
              tanhf_(u2) * ctx[k + 2] + tanhf_(u3) * ctx[k + 3];
    }
    part[w * 64 + lane] = accs;
    __syncthreads();
    if (t < 64) {
      float s = part[t] + part[64 + t] + part[128 + t] + part[192 + t];
      svals[a * 64 + t] = tanhf_(s);
    }
  }
  __syncthreads();

  const float* c0 = child + ((size_t)node * 4) * 8192;
  float* dst = h0 + (size_t)node * 8192;
#pragma unroll
  for (int i = 0; i < 8; ++i) {
    int f = t + 256 * i;
    int b = f >> 5;
    float s0 = svals[b], s1 = svals[64 + b], s2 = svals[128 + b], s3 = svals[192 + b];
    float m = fmaxf(fmaxf(s0, s1), fmaxf(s2, s3));
    float e0 = __expf(s0 - m), e1 = __expf(s1 - m), e2 = __expf(s2 - m), e3 = __expf(s3 - m);
    float inv = 1.0f / (e0 + e1 + e2 + e3);
    e0 *= inv; e1 *= inv; e2 *= inv; e3 *= inv;
    float4 v0 = *(const float4*)(c0 + (f << 2));
    float4 v1 = *(const float4*)(c0 + 8192 + (f << 2));
    float4 v2 = *(const float4*)(c0 + 16384 + (f << 2));
    float4 v3 = *(const float4*)(c0 + 24576 + (f << 2));
    float4 r;
    r.x = e0 * v0.x + e1 * v1.x + e2 * v2.x + e3 * v3.x;
    r.y = e0 * v0.y + e1 * v1.y + e2 * v2.y + e3 * v3.y;
    r.z = e0 * v0.z + e1 * v1.z + e2 * v2.z + e3 * v3.z;
    r.w = e0 * v0.w + e1 * v1.w + e2 * v2.w + e3 * v3.w;
    *(float4*)(dst + (f << 2)) = r;
  }
}

// per-level max over nodes, chunked across blockIdx.y; encoded atomicMax
__global__ __launch_bounds__(256) void reduce_kernel(const float* __restrict__ h, int n,
                                                     unsigned* __restrict__ acc) {
  int out = blockIdx.x * 256 + threadIdx.x;   // 0..8191
  int n0 = blockIdx.y * 32;
  int n1 = n0 + 32 < n ? n0 + 32 : n;
  float m = -3.4e38f;
  for (int node = n0; node < n1; ++node)
    m = fmaxf(m, h[(size_t)node * 8192 + out]);
  atomicMax(&acc[out], fenc(m));
}

extern "C" void kernel_launch(void* const* d_in, const int* in_sizes, int n_in,
                              void* d_out, int out_size, void* d_ws, size_t ws_size,
                              hipStream_t stream) {
  const int*   tokens = (const int*)d_in[0];
  const float* emb    = (const float*)d_in[1];
  const float* sent_w = (const float*)d_in[2];
  const float* sent_b = (const float*)d_in[3];
  const float* ctx_w  = (const float*)d_in[4];
  const float* w_ih   = (const float*)d_in[5];
  const float* w_hh   = (const float*)d_in[6];
  const float* b_ih   = (const float*)d_in[7];
  const float* b_hh   = (const float*)d_in[8];

  char* ws = (char*)d_ws;
  unsigned* acc = (unsigned*)(ws + WS_ACC_OFF);
  float* swT = (float*)(ws + WS_SWT_OFF);
  float* hA  = (float*)(ws + WS_HA_OFF);
  float* hB  = (float*)(ws + WS_HB_OFF);
  float* h0b = (float*)(ws + WS_H0_OFF);

  hipLaunchKernelGGL(init_acc, dim3(32), dim3(256), 0, stream, acc);
  hipLaunchKernelGGL(prep_swt, dim3(64), dim3(256), 0, stream, sent_w, swT);

  static const int offs[7] = {0, 1, 5, 21, 85, 341, 1365};
  float* child = nullptr;
  for (int d = 6; d >= 0; --d) {
    int n = 1 << (2 * d);
    int off = offs[d];
    float* hout = (d & 1) ? hB : hA;
    int jsplit = (d >= 5) ? 1 : (d == 4 ? 2 : 8);

    if (d < 6) {
      hipLaunchKernelGGL(attn_kernel, dim3(n), dim3(256), 0, stream,
                         child, swT, sent_b, ctx_w, h0b);
      hipLaunchKernelGGL(gru_kernel<true>, dim3(n, jsplit), dim3(256), 0, stream,
                         tokens + (size_t)off * 64, emb, w_ih, w_hh, b_ih, b_hh,
                         h0b, hout);
    } else {
      hipLaunchKernelGGL(gru_kernel<false>, dim3(n, jsplit), dim3(256), 0, stream,
                         tokens + (size_t)off * 64, emb, w_ih, w_hh, b_ih, b_hh,
                         (const float*)nullptr, hout);
    }
    hipLaunchKernelGGL(reduce_kernel, dim3(32, (n + 31) / 32), dim3(256), 0, stream,
                       hout, n, acc);
    child = hout;
  }
  hipLaunchKernelGGL(decode_out, dim3(32), dim3(256), 0, stream, acc, (float*)d_out);
}

// Round 2
// 376.136 us; speedup vs baseline: 5.8395x; 5.8395x over previous
//
#include <hip/hip_runtime.h>
#include <cstdint>
#include <cstddef>

// ---------------------------------------------------------------------------
// BatchTreeEncoder on MFMA: A=4, D=7, B=64, E=128, H=128, N_NODES=5461
// All GEMMs in bf16 mfma_f32_16x16x32_bf16, fp32 accumulate.
// h stored bf16. Output max via sliced encoded atomicMax (fp32 values).
// ---------------------------------------------------------------------------

typedef short  bf16x8 __attribute__((ext_vector_type(8)));
typedef float  f32x4  __attribute__((ext_vector_type(4)));

// workspace layout (bytes)
#define WS_ACC   0u                      // 32*8192*4 = 1 MB
#define WS_WIH   1048576u                // 384*128*2 = 96 KB
#define WS_WHH   (WS_WIH + 98304u)
#define WS_SWT   (WS_WHH + 98304u)       // 128*128*2 = 32 KB
#define WS_HA    2097152u                // 4096*64*128*2 = 64 MB (even levels)
#define WS_HB    (WS_HA + 67108864u)     // 16 MB (odd levels)
#define WS_H0    (WS_HB + 16777216u)     // 16 MB (attention out)
// total ~98 MB

__device__ __forceinline__ float sigm(float x)   { return 1.0f / (1.0f + __expf(-x)); }
__device__ __forceinline__ float tanhf_(float x) { return 1.0f - 2.0f / (1.0f + __expf(2.0f * x)); }

__device__ __forceinline__ unsigned short f2b(float f) {
  unsigned u = __float_as_uint(f);
  u += 0x7fffu + ((u >> 16) & 1u);     // RNE (no NaN here)
  return (unsigned short)(u >> 16);
}
__device__ __forceinline__ float b2f(unsigned short s) {
  return __uint_as_float(((unsigned)s) << 16);
}

__device__ __forceinline__ unsigned fenc(float f) {
  unsigned u = __float_as_uint(f);
  return (u & 0x80000000u) ? ~u : (u | 0x80000000u);
}
__device__ __forceinline__ float fdec(unsigned e) {
  unsigned u = (e & 0x80000000u) ? (e & 0x7fffffffu) : ~e;
  return __uint_as_float(u);
}

__device__ __forceinline__ f32x4 mfma16(bf16x8 a, bf16x8 b, f32x4 c) {
  return __builtin_amdgcn_mfma_f32_16x16x32_bf16(a, b, c, 0, 0, 0);
}

__global__ __launch_bounds__(256) void init_acc(unsigned* __restrict__ acc) {
  acc[blockIdx.x * 256 + threadIdx.x] = 0u;            // grid 1024
}

__global__ __launch_bounds__(256) void decode_out(const unsigned* __restrict__ acc,
                                                  float* __restrict__ out) {
  int i = blockIdx.x * 256 + threadIdx.x;              // grid 32
  unsigned m = 0u;
  for (int s = 0; s < 32; ++s) m = max(m, acc[s * 8192 + i]);
  out[i] = fdec(m);
}

// fp32 -> bf16 weight conversion + sent_w transpose (swt[k][h] = sent_w[h][k])
__global__ __launch_bounds__(256) void prep(const float* __restrict__ wih,
                                            const float* __restrict__ whh,
                                            const float* __restrict__ sw,
                                            unsigned short* __restrict__ wihb,
                                            unsigned short* __restrict__ whhb,
                                            unsigned short* __restrict__ swtb) {
  int i = blockIdx.x * 256 + threadIdx.x;              // grid 448 = 114688
  if (i < 49152)       wihb[i] = f2b(wih[i]);
  else if (i < 98304)  whhb[i - 49152] = f2b(whh[i - 49152]);
  else { int j = i - 98304; int k = j >> 7, h = j & 127; swtb[j] = f2b(sw[h * 128 + k]); }
}

// ---------------------------------------------------------------------------
// GRU: grid (n, 2), block 256 (4 waves). Wave owns 16 outputs j = gy*64+w*16+l.
// Gate triplet cols {j, 128+j, 256+j}; r,z over concat-K=256 [x || h0];
// n-gate split accumulators (Cn from x, Ch from h0). B-frags in registers.
// A in LDS, XOR-swizzled 16B chunks (conflict-free b128 reads).
// ---------------------------------------------------------------------------
template <bool HAS_H>
__global__ __launch_bounds__(256, 2) void gru_mfma(
    const int*            __restrict__ tok,
    const float*          __restrict__ emb,
    const unsigned short* __restrict__ wih,
    const unsigned short* __restrict__ whh,
    const float*          __restrict__ b_ih,
    const float*          __restrict__ b_hh,
    const unsigned short* __restrict__ h0,
    unsigned short*       __restrict__ hout,
    unsigned*             __restrict__ acc)
{
  constexpr int RS  = HAS_H ? 256 : 128;   // ushorts per LDS row
  constexpr int NKS = HAS_H ? 8 : 4;
  __shared__ unsigned short lds[64 * RS];

  const int node = blockIdx.x;
  const int t = threadIdx.x;

  // stage x (emb gather, fp32 -> bf16), rows m=batch, chunks c of 8 bf16
  {
    const int* tp = tok + node * 64;
#pragma unroll
    for (int i = 0; i < 8; ++i) {
      int f = t + 256 * i;            // 0..2047
      int m = f >> 5, q4 = f & 31;    // row, float4 index
      float4 v = *(const float4*)(emb + (size_t)tp[m] * 128 + q4 * 4);
      int c = q4 >> 1, half = q4 & 1;
      ushort4 o; o.x = f2b(v.x); o.y = f2b(v.y); o.z = f2b(v.z); o.w = f2b(v.w);
      *(ushort4*)(lds + m * RS + ((c ^ (m & 15)) << 3) + (half << 2)) = o;
    }
  }
  if constexpr (HAS_H) {              // stage h0 (bf16 16B chunks), chunks 16..31
    const unsigned short* hp = h0 + (size_t)node * 8192;
#pragma unroll
    for (int i = 0; i < 4; ++i) {
      int g = t + 256 * i;            // 0..1023
      int m = g >> 4, c16 = g & 15;
      uint4 v = *(const uint4*)(hp + m * 128 + c16 * 8);
      *(uint4*)(lds + m * 256 + ((16 | ((c16 ^ (m & 15)) & 15)) << 3)) = v;
    }
  }

  const int w = __builtin_amdgcn_readfirstlane(t >> 6);
  const int lane = t & 63, l = lane & 15, q = lane >> 4;
  const int j = blockIdx.y * 64 + w * 16 + l;

  // B fragments in registers (rows of W are GEMM cols; frag = 8 contig k)
  bf16x8 Br[NKS], Bz[NKS], Bn[4], Bh[HAS_H ? 4 : 1];
#pragma unroll
  for (int ks = 0; ks < 4; ++ks) {
    const int ko = ks * 32 + q * 8;
    Br[ks] = *(const bf16x8*)(wih + (size_t)j * 128 + ko);
    Bz[ks] = *(const bf16x8*)(wih + (size_t)(128 + j) * 128 + ko);
    Bn[ks] = *(const bf16x8*)(wih + (size_t)(256 + j) * 128 + ko);
    if constexpr (HAS_H) {
      Br[4 + ks] = *(const bf16x8*)(whh + (size_t)j * 128 + ko);
      Bz[4 + ks] = *(const bf16x8*)(whh + (size_t)(128 + j) * 128 + ko);
      Bh[ks]     = *(const bf16x8*)(whh + (size_t)(256 + j) * 128 + ko);
    }
  }

  f32x4 Cr[4] = {{0,0,0,0},{0,0,0,0},{0,0,0,0},{0,0,0,0}};
  f32x4 Cz[4] = {{0,0,0,0},{0,0,0,0},{0,0,0,0},{0,0,0,0}};
  f32x4 Cn[4] = {{0,0,0,0},{0,0,0,0},{0,0,0,0},{0,0,0,0}};
  f32x4 Ch[4] = {{0,0,0,0},{0,0,0,0},{0,0,0,0},{0,0,0,0}};
  __syncthreads();

#pragma unroll
  for (int ks = 0; ks < NKS; ++ks) {
    bf16x8 A[4];
#pragma unroll
    for (int mt = 0; mt < 4; ++mt) {
      int m = mt * 16 + l;
      int c = ks * 4 + q;
      A[mt] = *(const bf16x8*)(lds + m * RS + (((c & 16) | ((c ^ l) & 15)) << 3));
    }
#pragma unroll
    for (int mt = 0; mt < 4; ++mt) {
      Cr[mt] = mfma16(A[mt], Br[ks], Cr[mt]);
      Cz[mt] = mfma16(A[mt], Bz[ks], Cz[mt]);
      if (!HAS_H || ks < 4) Cn[mt] = mfma16(A[mt], Bn[ks & 3], Cn[mt]);
      else                  Ch[mt] = mfma16(A[mt], Bh[ks - 4], Ch[mt]);
    }
  }

  // epilogue: gates in-register (triplet shares lane), bf16 store + atomicMax
  const float bR = b_ih[j] + b_hh[j];
  const float bZ = b_ih[128 + j] + b_hh[128 + j];
  const float bN = b_ih[256 + j];
  const float bH = b_hh[256 + j];
  unsigned* accs = acc + (node & 31) * 8192;

#pragma unroll
  for (int mt = 0; mt < 4; ++mt) {
#pragma unroll
    for (int e = 0; e < 4; ++e) {
      const int b = mt * 16 + q * 4 + e;        // C/D: col=lane&15, row=quad*4+reg
      float r  = sigm(Cr[mt][e] + bR);
      float z  = sigm(Cz[mt][e] + bZ);
      float hn_ = bH + (HAS_H ? Ch[mt][e] : 0.0f);
      float nv = tanhf_(Cn[mt][e] + bN + r * hn_);
      float hp = 0.0f;
      if constexpr (HAS_H) {
        int c16 = j >> 3;
        hp = b2f(lds[b * 256 + ((16 | ((c16 ^ (b & 15)) & 15)) << 3) + (j & 7)]);
      }
      float hv = (1.0f - z) * nv + z * hp;
      hout[(size_t)(node * 64 + b) * 128 + j] = f2b(hv);
      atomicMax(accs + b * 128 + j, fenc(hv));
    }
  }
}

// ---------------------------------------------------------------------------
// Attention: grid n (parents), block 512 (8 waves: wm=row-half, wn=col-chunk32).
// u = ch(256x128) . sent_w via MFMA; s = tanh(sum_k tanh(u+sb)*ctx);
// softmax over a; h0 = sum_a alpha_a * ch_a.
// ---------------------------------------------------------------------------
__global__ __launch_bounds__(512, 2) void attn_mfma(
    const unsigned short* __restrict__ hch,   // child h, rows p*256..
    const unsigned short* __restrict__ swt,   // 128x128 bf16 [k_u][h]
    const float*          __restrict__ sb,
    const float*          __restrict__ ctx,
    unsigned short*       __restrict__ h0out)
{
  __shared__ unsigned short chs[256 * 128];   // 64 KB, swizzled
  __shared__ float spart[4][256];
  __shared__ float alf[256];

  const int p = blockIdx.x;
  const int t = threadIdx.x;

  const unsigned short* src = hch + (size_t)p * 256 * 128;
#pragma unroll
  for (int i = 0; i < 8; ++i) {
    int g = t + 512 * i;                      // 0..4095 16B-chunks
    int m = g >> 4, c = g & 15;
    uint4 v = *(const uint4*)(src + m * 128 + c * 8);
    *(uint4*)(chs + m * 128 + ((c ^ (m & 15)) << 3)) = v;
  }

  const int w = __builtin_amdgcn_readfirstlane(t >> 6);
  const int wm = w >> 2, wn = w & 3;
  const int lane = t & 63, l = lane & 15, q = lane >> 4;

  bf16x8 Bs[2][4];
#pragma unroll
  for (int nt = 0; nt < 2; ++nt)
#pragma unroll
    for (int ks = 0; ks < 4; ++ks)
      Bs[nt][ks] = *(const bf16x8*)(swt + (size_t)(wn * 32 + nt * 16 + l) * 128 + ks * 32 + q * 8);

  f32x4 Cu[8][2] = {};
  __syncthreads();

#pragma unroll
  for (int ks = 0; ks < 4; ++ks) {
#pragma unroll
    for (int mt = 0; mt < 8; ++mt) {
      int m = wm * 128 + mt * 16 + l;
      int c = ks * 4 + q;
      bf16x8 A = *(const bf16x8*)(chs + m * 128 + (((c ^ (m & 15)) & 15) << 3));
      Cu[mt][0] = mfma16(A, Bs[0][ks], Cu[mt][0]);
      Cu[mt][1] = mfma16(A, Bs[1][ks], Cu[mt][1]);
    }
  }

  const float sb0 = sb[wn * 32 + l],  sb1 = sb[wn * 32 + 16 + l];
  const float cx0 = ctx[wn * 32 + l], cx1 = ctx[wn * 32 + 16 + l];
#pragma unroll
  for (int mt = 0; mt < 8; ++mt) {
    float pe[4];
#pragma unroll
    for (int e = 0; e < 4; ++e)
      pe[e] = tanhf_(Cu[mt][0][e] + sb0) * cx0 + tanhf_(Cu[mt][1][e] + sb1) * cx1;
#pragma unroll
    for (int mask = 1; mask < 16; mask <<= 1)
#pragma unroll
      for (int e = 0; e < 4; ++e)
        pe[e] += __shfl_xor(pe[e], mask, 16);
    if (l == 0) {
      int r = wm * 128 + mt * 16 + q * 4;
#pragma unroll
      for (int e = 0; e < 4; ++e) spart[wn][r + e] = pe[e];
    }
  }
  __syncthreads();

  if (t < 256) {
    float s = tanhf_(spart[0][t] + spart[1][t] + spart[2][t] + spart[3][t]);
    spart[0][t] = s;                          // reuse row 0 as s-values
  }
  __syncthreads();
  if (t < 64) {
    float s0 = spart[0][t], s1 = spart[0][64 + t], s2 = spart[0][128 + t], s3 = spart[0][192 + t];
    float m = fmaxf(fmaxf(s0, s1), fmaxf(s2, s3));
    float e0 = __expf(s0 - m), e1 = __expf(s1 - m), e2 = __expf(s2 - m), e3 = __expf(s3 - m);
    float inv = 1.0f / (e0 + e1 + e2 + e3);
    alf[t] = e0 * inv; alf[64 + t] = e1 * inv; alf[128 + t] = e2 * inv; alf[192 + t] = e3 * inv;
  }
  __syncthreads();

#pragma unroll
  for (int i = 0; i < 2; ++i) {
    int id = t + 512 * i;                     // 0..1023: (b, chunk)
    int b = id >> 4, c = id & 15;
    float o[8] = {0,0,0,0,0,0,0,0};
#pragma unroll
    for (int a = 0; a < 4; ++a) {
      int m = a * 64 + b;
      const unsigned short* rp = chs + m * 128 + ((c ^ (m & 15)) << 3);
      float al = alf[a * 64 + b];
#pragma unroll
      for (int k = 0; k < 8; ++k) o[k] += al * b2f(rp[k]);
    }
    ushort4 o0, o1;
    o0.x = f2b(o[0]); o0.y = f2b(o[1]); o0.z = f2b(o[2]); o0.w = f2b(o[3]);
    o1.x = f2b(o[4]); o1.y = f2b(o[5]); o1.z = f2b(o[6]); o1.w = f2b(o[7]);
    *(ushort4*)(h0out + (size_t)(p * 64 + b) * 128 + c * 8)     = o0;
    *(ushort4*)(h0out + (size_t)(p * 64 + b) * 128 + c * 8 + 4) = o1;
  }
}

extern "C" void kernel_launch(void* const* d_in, const int* in_sizes, int n_in,
                              void* d_out, int out_size, void* d_ws, size_t ws_size,
                              hipStream_t stream) {
  const int*   tokens = (const int*)d_in[0];
  const float* emb    = (const float*)d_in[1];
  const float* sent_w = (const float*)d_in[2];
  const float* sent_b = (const float*)d_in[3];
  const float* ctx_w  = (const float*)d_in[4];
  const float* w_ih   = (const float*)d_in[5];
  const float* w_hh   = (const float*)d_in[6];
  const float* b_ih   = (const float*)d_in[7];
  const float* b_hh   = (const float*)d_in[8];

  char* ws = (char*)d_ws;
  unsigned*       acc  = (unsigned*)(ws + WS_ACC);
  unsigned short* wihb = (unsigned short*)(ws + WS_WIH);
  unsigned short* whhb = (unsigned short*)(ws + WS_WHH);
  unsigned short* swtb = (unsigned short*)(ws + WS_SWT);
  unsigned short* hA   = (unsigned short*)(ws + WS_HA);
  unsigned short* hB   = (unsigned short*)(ws + WS_HB);
  unsigned short* h0b  = (unsigned short*)(ws + WS_H0);

  hipLaunchKernelGGL(init_acc, dim3(1024), dim3(256), 0, stream, acc);
  hipLaunchKernelGGL(prep, dim3(448), dim3(256), 0, stream,
                     w_ih, w_hh, sent_w, wihb, whhb, swtb);

  static const int offs[7] = {0, 1, 5, 21, 85, 341, 1365};
  for (int d = 6; d >= 0; --d) {
    int n = 1 << (2 * d);
    int off = offs[d];
    unsigned short* hout = (d & 1) ? hB : hA;
    if (d < 6) {
      unsigned short* child = (d & 1) ? hA : hB;   // level d+1 output
      hipLaunchKernelGGL(attn_mfma, dim3(n), dim3(512), 0, stream,
                         child, swtb, sent_b, ctx_w, h0b);
      hipLaunchKernelGGL((gru_mfma<true>), dim3(n, 2), dim3(256), 0, stream,
                         tokens + (size_t)off * 64, emb, wihb, whhb, b_ih, b_hh,
                         h0b, hout, acc);
    } else {
      hipLaunchKernelGGL((gru_mfma<false>), dim3(n, 2), dim3(256), 0, stream,
                         tokens + (size_t)off * 64, emb, wihb, whhb, b_ih, b_hh,
                         (const unsigned short*)nullptr, hout, acc);
    }
  }
  hipLaunchKernelGGL(decode_out, dim3(32), dim3(256), 0, stream, acc, (float*)d_out);
}